// Round 15
// baseline (368.166 us; speedup 1.0000x reference)
//
#include <hip/hip_runtime.h>
#include <math.h>

constexpr int NN = 100000;
constexpr int NE = 1600000;
constexpr int NG = 512;
constexpr int NBKT = (NN + 127) / 128;   // 782 dst-buckets (128 nodes each)
constexpr int BSTR = 2560;               // fixed bucket capacity (mean 2048, sd 45 -> 11 sigma)
constexpr int PADREG = BSTR + 896;       // padded csr region per bucket
constexpr int BCAP = 3072;               // LDS staging capacity

typedef unsigned short bf16_t;
__device__ __forceinline__ bf16_t f2bf(float f) {
    unsigned u = __float_as_uint(f);
    unsigned r = (u + 0x7fffu + ((u >> 16) & 1u)) >> 16;   // round-nearest-even
    return (bf16_t)r;
}
__device__ __forceinline__ float bflo(unsigned u) { return __uint_as_float(u << 16); }
__device__ __forceinline__ float bfhi(unsigned u) { return __uint_as_float(u & 0xffff0000u); }
__device__ __forceinline__ unsigned bfpack(float lo, float hi) {
    return ((unsigned)f2bf(hi) << 16) | (unsigned)f2bf(lo);
}
__device__ __forceinline__ float bf2f(bf16_t h) {
    return __uint_as_float(((unsigned)h) << 16);
}
__device__ __forceinline__ float eluf(float x) {
    return x > 0.f ? x : expm1f(x);
}

// LDS-aggregated bucket scatter into FIXED-STRIDE regions.
// 384 blocks: ~4.2k edges/block, one global atomic per (block,bucket).
__global__ __launch_bounds__(256) void k_scatter_bkt(const int* __restrict__ src,
                                                     const int* __restrict__ dst,
                                                     int* __restrict__ bktCur,
                                                     int* __restrict__ ebuf) {
    __shared__ int cnt[NBKT];
    __shared__ int base[NBKT];
    int tid = threadIdx.x;
    for (int i = tid; i < NBKT; i += 256) cnt[i] = 0;
    __syncthreads();
    int per = (NE + gridDim.x - 1) / gridDim.x;
    int e0 = blockIdx.x * per;
    int e1 = min(e0 + per, NE);
    for (int e = e0 + tid; e < e1; e += 256) {
        int d = __builtin_nontemporal_load(dst + e);
        atomicAdd(&cnt[d >> 7], 1);
    }
    __syncthreads();
    for (int i = tid; i < NBKT; i += 256) {
        int c = cnt[i];
        base[i] = i * BSTR + (c ? atomicAdd(&bktCur[i], c) : 0);
        cnt[i] = 0;                 // reuse as local cursor
    }
    __syncthreads();
    for (int e = e0 + tid; e < e1; e += 256) {
        int s = __builtin_nontemporal_load(src + e);
        int d = __builtin_nontemporal_load(dst + e);
        int b = d >> 7;
        int off = atomicAdd(&cnt[b], 1);
        ebuf[base[b] + off] = (s << 7) | (d & 127);
    }
}

// per-bucket LDS counting sort -> PADDED csr rows (mult of 8, sentinel NN) +
// rowInfo + dinv + ORDER: nodes of each bucket emitted grouped by padded-degree
// bin (pcnt/8) so a gather wave's 8 groups get near-equal round counts.
// Extra block (blockIdx == NBKT) computes gptr from the sorted batch array.
__global__ __launch_bounds__(256) void k_bktsort(const int* __restrict__ bktCur,
                                                 const int* __restrict__ ebuf,
                                                 int* __restrict__ csr,
                                                 int2* __restrict__ rowInfo,
                                                 float* __restrict__ dinv,
                                                 int* __restrict__ order,
                                                 const int* __restrict__ batch,
                                                 int* __restrict__ gptr) {
    int b = blockIdx.x, tid = threadIdx.x;
    if (b == NBKT) {                                  // gptr block
        for (int g = tid; g <= NG; g += 256) {
            if (g == NG) { gptr[NG] = NN; continue; }
            int lo = 0, hi = NN;
            while (lo < hi) {
                int mid = (lo + hi) >> 1;
                if (batch[mid] < g) lo = mid + 1; else hi = mid;
            }
            gptr[g] = lo;
        }
        return;
    }
    __shared__ int sbuf[BCAP];
    __shared__ int cnt[128], scn[128], cur[128];
    __shared__ int cnt2[32], cur2[32];
    __shared__ int padTotS;
    int base = b * BSTR;
    int n = min(bktCur[b], BSTR);
    int pbase = b * PADREG;                           // 8-aligned (PADREG % 8 == 0)
    for (int i = tid; i < n; i += 256) sbuf[i] = __builtin_nontemporal_load(ebuf + base + i);
    if (tid < 128) cnt[tid] = 0;
    if (tid >= 128 && tid < 160) cnt2[tid - 128] = 0;
    __syncthreads();
    for (int i = tid; i < n; i += 256) atomicAdd(&cnt[sbuf[i] & 127], 1);
    __syncthreads();
    int deg = (tid < 128) ? cnt[tid] : 0;
    int pcnt = (deg + 7) & ~7;
    if (tid < 128) scn[tid] = pcnt;
    __syncthreads();
    for (int off = 1; off < 128; off <<= 1) {
        int t = (tid < 128 && tid >= off) ? scn[tid - off] : 0;
        __syncthreads();
        if (tid < 128) scn[tid] += t;
        __syncthreads();
    }
    int node = b * 128 + tid;
    int key = min(pcnt >> 3, 31);
    if (tid == 127) padTotS = scn[127];
    if (tid < 128) {
        int ex = scn[tid] - pcnt;
        cur[tid] = ex;
        if (node < NN) {
            rowInfo[node] = make_int2(pbase + ex, pbase + ex + pcnt);
            dinv[node] = rsqrtf((float)deg + 1.0f);
            atomicAdd(&cnt2[key], 1);
        }
    }
    __syncthreads();
    if (tid == 0) {                                   // tiny serial scan over 32 bins
        int run = 0;
#pragma unroll
        for (int i = 0; i < 32; ++i) { int c = cnt2[i]; cur2[i] = run; run += c; }
    }
    __syncthreads();
    if (tid < 128 && node < NN) {
        int pos = atomicAdd(&cur2[key], 1);
        order[b * 128 + pos] = node;                  // degree-binned permutation
    }
    int padTot = padTotS;
    for (int i = tid; i < padTot; i += 256) csr[pbase + i] = NN;   // sentinel fill
    __syncthreads();
    for (int i = tid; i < n; i += 256) {
        int p = sbuf[i];
        int pos = atomicAdd(&cur[p & 127], 1);
        csr[pbase + pos] = p >> 7;
    }
}

// LDS-tiled layer-1 GEMM; epilogue writes y1 in SLICE-BLOCKED layout:
// slice s (cols 16s..16s+15) contiguous, region stride (NN+1)*16 bf16 (3.2 MB).
__global__ void k_gemm1(const float* __restrict__ x, const float* __restrict__ W1,
                        const float* __restrict__ dinv, bf16_t* __restrict__ y1b) {
    __shared__ float sx[64 * 66];
    __shared__ float sw[66 * 64];
    int tid = threadIdx.x;
    for (int i = tid; i < 66 * 32; i += 256) ((float2*)sw)[i] = ((const float2*)W1)[i];
    int base = blockIdx.x * 64;
    int rows = min(64, NN - base);
    int cnt2v = rows * 33;
    const float2* xp = (const float2*)(x + base * 66);
    for (int i = tid; i < cnt2v; i += 256) ((float2*)sx)[i] = xp[i];
    __syncthreads();
    int c = tid & 63, rg = tid >> 6;
    float acc[16];
#pragma unroll
    for (int i = 0; i < 16; ++i) acc[i] = 0.f;
    for (int k = 0; k < 66; ++k) {
        float wv = sw[k * 64 + c];
#pragma unroll
        for (int rr = 0; rr < 16; ++rr)
            acc[rr] = fmaf(sx[(rg * 16 + rr) * 66 + k], wv, acc[rr]);
    }
    bf16_t* dstp = y1b + (c >> 4) * ((NN + 1) * 16) + (c & 15);
#pragma unroll
    for (int rr = 0; rr < 16; ++rr) {
        int nn = base + rg * 16 + rr;
        if (nn < NN) dstp[nn * 16] = f2bf(dinv[nn] * acc[rr]);
        else if (nn == NN) dstp[nn * 16] = 0;     // sentinel zero row (all slices)
    }
}

// Slice-blocked CSR gather, degree-ordered nodes (order[]): a wave's 8 groups
// process nodes with near-equal padded degree -> minimal lockstep waste.
// Group of 8 lanes per node; one 32-B slice-row read per edge; 8-edge rounds.
template<int NSL>   // 4 for C=64, 2 for C=32
__global__ __launch_bounds__(256) void k_gather(const int2* __restrict__ rowInfo,
                                                const int* __restrict__ csr,
                                                const float* __restrict__ dinv,
                                                const int* __restrict__ order,
                                                const unsigned* __restrict__ yb,
                                                unsigned* __restrict__ aggb,
                                                float* __restrict__ sums,
                                                float* __restrict__ sqs) {
    constexpr int SH = (NSL == 4) ? 2 : 1;
    __shared__ float sSum[16], sSq[16];
    int tid = threadIdx.x;
    if (tid < 16) { sSum[tid] = 0.f; sSq[tid] = 0.f; }
    __syncthreads();
    int slice = blockIdx.x & (NSL - 1);
    int part = blockIdx.x >> SH;
    int nparts = gridDim.x >> SH;
    int lane = tid & 7;
    int grp = tid >> 3;                           // 32 node-groups per block
    const unsigned* y = yb + (size_t)slice * (NN + 1) * 8;
    unsigned* agg = aggb + (size_t)slice * NN * 8;
    float s0 = 0.f, s1 = 0.f, q0 = 0.f, q1 = 0.f;
    for (int idx = part * 32 + grp; idx < NN; idx += nparts * 32) {
        int n = order[idx];
        int2 ri = rowInfo[n];
        float a0 = 0.f, a1 = 0.f;
        for (int j = ri.x; j < ri.y; j += 8) {
            const unsigned long long* cp = (const unsigned long long*)(csr + j);
            unsigned long long p0 = __builtin_nontemporal_load(cp);
            unsigned long long p1 = __builtin_nontemporal_load(cp + 1);
            unsigned long long p2 = __builtin_nontemporal_load(cp + 2);
            unsigned long long p3 = __builtin_nontemporal_load(cp + 3);
            unsigned v0 = y[(int)(p0 & 0xffffffffu) * 8 + lane];
            unsigned v1 = y[(int)(p0 >> 32) * 8 + lane];
            unsigned v2 = y[(int)(p1 & 0xffffffffu) * 8 + lane];
            unsigned v3 = y[(int)(p1 >> 32) * 8 + lane];
            unsigned v4 = y[(int)(p2 & 0xffffffffu) * 8 + lane];
            unsigned v5 = y[(int)(p2 >> 32) * 8 + lane];
            unsigned v6 = y[(int)(p3 & 0xffffffffu) * 8 + lane];
            unsigned v7 = y[(int)(p3 >> 32) * 8 + lane];
            a0 += bflo(v0); a1 += bfhi(v0);
            a0 += bflo(v1); a1 += bfhi(v1);
            a0 += bflo(v2); a1 += bfhi(v2);
            a0 += bflo(v3); a1 += bfhi(v3);
            a0 += bflo(v4); a1 += bfhi(v4);
            a0 += bflo(v5); a1 += bfhi(v5);
            a0 += bflo(v6); a1 += bfhi(v6);
            a0 += bflo(v7); a1 += bfhi(v7);
        }
        unsigned vs = y[n * 8 + lane];            // self loop
        float di = dinv[n];
        a0 = di * (a0 + bflo(vs));
        a1 = di * (a1 + bfhi(vs));
        agg[n * 8 + lane] = bfpack(a0, a1);
        s0 += a0; q0 += a0 * a0;
        s1 += a1; q1 += a1 * a1;
    }
    atomicAdd(&sSum[lane * 2], s0);
    atomicAdd(&sSum[lane * 2 + 1], s1);
    atomicAdd(&sSq[lane * 2], q0);
    atomicAdd(&sSq[lane * 2 + 1], q1);
    __syncthreads();
    if (tid < 16) {
        unsafeAtomicAdd(&sums[slice * 16 + tid], sSum[tid]);
        unsafeAtomicAdd(&sqs[slice * 16 + tid], sSq[tid]);
    }
}

// fused: scale/shift from sums/sqs, h1 = elu(bn(agg1)) in LDS, y2 = dinv*(h1@W2).
// agg1 read slice-blocked; y2 written slice-blocked (2 slices). +1 block for sentinel.
__global__ void k_bn_gemm2(const unsigned* __restrict__ agg1b, const float* __restrict__ sums,
                           const float* __restrict__ sqs, const float* __restrict__ gamma,
                           const float* __restrict__ beta, const float* __restrict__ W2,
                           const float* __restrict__ dinv, bf16_t* __restrict__ y2b) {
    __shared__ float sh[8 * 64];
    __shared__ float sW[64 * 32];
    __shared__ float sscale[64], sshift[64];
    int tid = threadIdx.x;
    if (tid < 64) {
        float mu = sums[tid] * (1.0f / NN);
        float var = sqs[tid] * (1.0f / NN) - mu * mu;
        float sc = gamma[tid] * rsqrtf(var + 1e-5f);
        sscale[tid] = sc;
        sshift[tid] = beta[tid] - mu * sc;
    }
#pragma unroll
    for (int i = tid; i < 64 * 32; i += 256) sW[i] = W2[i];
    __syncthreads();
    int base = blockIdx.x * 8;
    {   // load 8 rows x 64 cols from 4 slice regions: thread t -> one uint (2 cols)
        int r = tid >> 5, q = tid & 31;
        int slice = q >> 3, lane = q & 7;
        int n = base + r;
        int col = slice * 16 + lane * 2;
        float v0 = 0.f, v1 = 0.f;
        if (n < NN) {
            unsigned u = agg1b[(size_t)slice * NN * 8 + n * 8 + lane];
            v0 = eluf(fmaf(bflo(u), sscale[col], sshift[col]));
            v1 = eluf(fmaf(bfhi(u), sscale[col + 1], sshift[col + 1]));
        }
        sh[r * 64 + col] = v0;
        sh[r * 64 + col + 1] = v1;
    }
    __syncthreads();
    int r = tid >> 5, c = tid & 31;
    int n = base + r;
    bf16_t* dstp = y2b + (c >> 4) * ((NN + 1) * 16) + (c & 15);
    if (n < NN) {
        float acc = 0.f;
#pragma unroll
        for (int k = 0; k < 64; ++k) acc = fmaf(sh[r * 64 + k], sW[k * 32 + c], acc);
        dstp[n * 16] = f2bf(dinv[n] * acc);
    } else if (n == NN) {
        dstp[n * 16] = 0;                         // sentinel zero row
    }
}

// fused: BN stats -> scale/shift, segment pool (no atomics), 2-layer MLP head.
// agg2 read from slice-blocked layout (2 slices of 16 cols).
__global__ void k_poolmlp(const unsigned* __restrict__ agg2b, const float* __restrict__ sums,
                          const float* __restrict__ sqs, const float* __restrict__ gamma,
                          const float* __restrict__ beta, const int* __restrict__ gptr,
                          const float* __restrict__ Wm1, const float* __restrict__ bm1,
                          const float* __restrict__ Wm2, const float* __restrict__ bm2,
                          float* __restrict__ out) {
    __shared__ float sscale[32], sshift[32];
    __shared__ float red[256];
    __shared__ float gr[64];
    __shared__ float h[32];
    int tid = threadIdx.x;
    if (tid < 32) {
        float mu = sums[tid] * (1.0f / NN);
        float var = sqs[tid] * (1.0f / NN) - mu * mu;
        float sc = gamma[tid] * rsqrtf(var + 1e-5f);
        sscale[tid] = sc;
        sshift[tid] = beta[tid] - mu * sc;
    }
    __syncthreads();
    int g = blockIdx.x;
    int c = tid & 31, r = tid >> 5;
    int beg = gptr[g], end = gptr[g + 1];
    float scl = sscale[c], shf = sshift[c];
    const unsigned* ap = agg2b + (size_t)(c >> 4) * NN * 8 + ((c >> 1) & 7);
    bool hi = (c & 1);
    float s = 0.f, m = -INFINITY;
    for (int n = beg + r; n < end; n += 8) {
        unsigned u = ap[n * 8];
        float v = eluf(fmaf(hi ? bfhi(u) : bflo(u), scl, shf));
        s += v;
        m = fmaxf(m, v);
    }
    red[tid] = s;
    __syncthreads();
    int cnt = end - beg;
    if (r == 0) {
        float stot = 0.f;
#pragma unroll
        for (int i = 0; i < 8; ++i) stot += red[i * 32 + c];
        gr[c] = stot / fmaxf((float)cnt, 1.f);
    }
    __syncthreads();
    red[tid] = m;
    __syncthreads();
    if (r == 0) {
        float mtot = -INFINITY;
#pragma unroll
        for (int i = 0; i < 8; ++i) mtot = fmaxf(mtot, red[i * 32 + c]);
        gr[32 + c] = (cnt > 0) ? mtot : 0.f;
    }
    __syncthreads();
    if (tid < 32) {
        float acc = bm1[tid];
#pragma unroll
        for (int k = 0; k < 64; ++k) acc = fmaf(gr[k], Wm1[k * 32 + tid], acc);
        h[tid] = eluf(acc);
    }
    __syncthreads();
    if (tid < 2) {
        float acc = bm2[tid];
#pragma unroll
        for (int k = 0; k < 32; ++k) acc = fmaf(h[k], Wm2[k * 2 + tid], acc);
        out[g * 2 + tid] = acc;
    }
}

extern "C" void kernel_launch(void* const* d_in, const int* in_sizes, int n_in,
                              void* d_out, int out_size, void* d_ws, size_t ws_size,
                              hipStream_t stream) {
    const float* x    = (const float*)d_in[0];
    const int*   eidx = (const int*)d_in[1];
    const int*   src  = eidx;
    const int*   dst  = eidx + NE;
    const int*   batch = (const int*)d_in[3];
    const float* W1  = (const float*)d_in[4];
    const float* g1  = (const float*)d_in[6];
    const float* be1 = (const float*)d_in[7];
    const float* W2  = (const float*)d_in[8];
    const float* g2  = (const float*)d_in[10];
    const float* be2 = (const float*)d_in[11];
    const float* Wm1 = (const float*)d_in[12];
    const float* bm1 = (const float*)d_in[13];
    const float* Wm2 = (const float*)d_in[14];
    const float* bm2 = (const float*)d_in[15];
    float* out = (float*)d_out;

    // ---- workspace layout ----
    constexpr int CSRSZ = NBKT * PADREG + 16;     // fixed-stride padded csr (~10.8 MB)
    int*    bktCur  = (int*)d_ws;                 // 800 -- zeroed
    float*  S       = (float*)(bktCur + 800);     // 512 stat floats -- zeroed
    int*    gptr    = (int*)(S + 512);            // 544
    int*    order   = gptr + 544;                 // 100000 (degree-binned perm)
    int*    csr     = order + 100000;             // CSRSZ (8-aligned rows)
    int2*   rowInfo = (int2*)(csr + CSRSZ);       // 100000
    float*  dinv    = (float*)(rowInfo + 100000); // 100000
    bf16_t* y1b     = (bf16_t*)(dinv + 100000);   // 4 slices x (NN+1)*16
    bf16_t* agg1b   = y1b + (NN + 1) * 64;        // 4 slices x NN*16
    bf16_t* y2b     = agg1b + NN * 64;            // 2 slices x (NN+1)*16
    bf16_t* agg2b   = y2b + (NN + 1) * 32;        // 2 slices x NN*16
    int*    ebuf    = (int*)y2b;                  // NBKT*BSTR ints (8 MB), aliases y2/agg2

    float* sum1 = S;        float* sq1 = S + 64;
    float* sum2 = S + 128;  float* sq2 = S + 160;

    // ---- init: bucket cursors + stats in one memset ----
    hipMemsetAsync(bktCur, 0, (800 + 512) * sizeof(int), stream);

    // ---- CSR build: LDS-agg fixed-stride scatter -> padded bucket sort (+order,+gptr) ----
    k_scatter_bkt<<<384, 256, 0, stream>>>(src, dst, bktCur, ebuf);
    k_bktsort<<<NBKT + 1, 256, 0, stream>>>(bktCur, ebuf, csr, rowInfo, dinv, order,
                                            batch, gptr);

    // ---- layer 1 (bias dropped: BN shift-invariant; y1 = dinv * xW1, blocked) ----
    k_gemm1<<<(NN + 63) / 64, 256, 0, stream>>>(x, W1, dinv, y1b);
    k_gather<4><<<4168, 256, 0, stream>>>(rowInfo, csr, dinv, order,
                                          (const unsigned*)y1b, (unsigned*)agg1b,
                                          sum1, sq1);

    // ---- layer 2 (BN+ELU+stats fused into GEMM; y2 = dinv * h1W2, blocked) ----
    k_bn_gemm2<<<NN / 8 + 1, 256, 0, stream>>>((const unsigned*)agg1b, sum1, sq1,
                                               g1, be1, W2, dinv, y2b);
    k_gather<2><<<2084, 256, 0, stream>>>(rowInfo, csr, dinv, order,
                                          (const unsigned*)y2b, (unsigned*)agg2b,
                                          sum2, sq2);

    // ---- pooling + MLP head in one kernel ----
    k_poolmlp<<<NG, 256, 0, stream>>>((const unsigned*)agg2b, sum2, sq2, g2, be2, gptr,
                                      Wm1, bm1, Wm2, bm2, out);
}

// Round 16
// 346.357 us; speedup vs baseline: 1.0630x; 1.0630x over previous
//
#include <hip/hip_runtime.h>
#include <math.h>

constexpr int NN = 100000;
constexpr int NE = 1600000;
constexpr int NG = 512;
constexpr int NBKT = (NN + 127) / 128;   // 782 dst-buckets (128 nodes each)
constexpr int BSTR = 2560;               // fixed bucket capacity (mean 2048, sd 45 -> 11 sigma)
constexpr int PADREG = BSTR + 896;       // padded csr region per bucket
constexpr int BCAP = 3072;               // LDS staging capacity

typedef unsigned short bf16_t;
__device__ __forceinline__ bf16_t f2bf(float f) {
    unsigned u = __float_as_uint(f);
    unsigned r = (u + 0x7fffu + ((u >> 16) & 1u)) >> 16;   // round-nearest-even
    return (bf16_t)r;
}
__device__ __forceinline__ float bflo(unsigned u) { return __uint_as_float(u << 16); }
__device__ __forceinline__ float bfhi(unsigned u) { return __uint_as_float(u & 0xffff0000u); }
__device__ __forceinline__ unsigned bfpack(float lo, float hi) {
    return ((unsigned)f2bf(hi) << 16) | (unsigned)f2bf(lo);
}
__device__ __forceinline__ float bf2f(bf16_t h) {
    return __uint_as_float(((unsigned)h) << 16);
}
__device__ __forceinline__ float eluf(float x) {
    return x > 0.f ? x : expm1f(x);
}

// LDS-aggregated bucket scatter into FIXED-STRIDE regions.
// 384 blocks (R15-verified ~10us win vs 128): one global atomic per (block,bucket).
__global__ __launch_bounds__(256) void k_scatter_bkt(const int* __restrict__ src,
                                                     const int* __restrict__ dst,
                                                     int* __restrict__ bktCur,
                                                     int* __restrict__ ebuf) {
    __shared__ int cnt[NBKT];
    __shared__ int base[NBKT];
    int tid = threadIdx.x;
    for (int i = tid; i < NBKT; i += 256) cnt[i] = 0;
    __syncthreads();
    int per = (NE + gridDim.x - 1) / gridDim.x;
    int e0 = blockIdx.x * per;
    int e1 = min(e0 + per, NE);
    for (int e = e0 + tid; e < e1; e += 256) {
        int d = __builtin_nontemporal_load(dst + e);
        atomicAdd(&cnt[d >> 7], 1);
    }
    __syncthreads();
    for (int i = tid; i < NBKT; i += 256) {
        int c = cnt[i];
        base[i] = i * BSTR + (c ? atomicAdd(&bktCur[i], c) : 0);
        cnt[i] = 0;                 // reuse as local cursor
    }
    __syncthreads();
    for (int e = e0 + tid; e < e1; e += 256) {
        int s = __builtin_nontemporal_load(src + e);
        int d = __builtin_nontemporal_load(dst + e);
        int b = d >> 7;
        int off = atomicAdd(&cnt[b], 1);
        ebuf[base[b] + off] = (s << 7) | (d & 127);
    }
}

// per-bucket LDS counting sort -> PADDED csr rows (mult of 8, sentinel NN),
// fixed-stride bucket regions; emits rowInfo{beg,end} + dinv.
// Extra block (blockIdx == NBKT) computes gptr from the sorted batch array.
__global__ __launch_bounds__(256) void k_bktsort(const int* __restrict__ bktCur,
                                                 const int* __restrict__ ebuf,
                                                 int* __restrict__ csr,
                                                 int2* __restrict__ rowInfo,
                                                 float* __restrict__ dinv,
                                                 const int* __restrict__ batch,
                                                 int* __restrict__ gptr) {
    int b = blockIdx.x, tid = threadIdx.x;
    if (b == NBKT) {                                  // gptr block
        for (int g = tid; g <= NG; g += 256) {
            if (g == NG) { gptr[NG] = NN; continue; }
            int lo = 0, hi = NN;
            while (lo < hi) {
                int mid = (lo + hi) >> 1;
                if (batch[mid] < g) lo = mid + 1; else hi = mid;
            }
            gptr[g] = lo;
        }
        return;
    }
    __shared__ int sbuf[BCAP];
    __shared__ int cnt[128], scn[128], cur[128];
    __shared__ int padTotS;
    int base = b * BSTR;
    int n = min(bktCur[b], BSTR);
    int pbase = b * PADREG;                           // 8-aligned (PADREG % 8 == 0)
    for (int i = tid; i < n; i += 256) sbuf[i] = __builtin_nontemporal_load(ebuf + base + i);
    if (tid < 128) cnt[tid] = 0;
    __syncthreads();
    for (int i = tid; i < n; i += 256) atomicAdd(&cnt[sbuf[i] & 127], 1);
    __syncthreads();
    int deg = (tid < 128) ? cnt[tid] : 0;
    int pcnt = (deg + 7) & ~7;
    if (tid < 128) scn[tid] = pcnt;
    __syncthreads();
    for (int off = 1; off < 128; off <<= 1) {
        int t = (tid < 128 && tid >= off) ? scn[tid - off] : 0;
        __syncthreads();
        if (tid < 128) scn[tid] += t;
        __syncthreads();
    }
    if (tid == 127) padTotS = scn[127];
    if (tid < 128) {
        int ex = scn[tid] - pcnt;
        cur[tid] = ex;
        int node = b * 128 + tid;
        if (node < NN) {
            rowInfo[node] = make_int2(pbase + ex, pbase + ex + pcnt);
            dinv[node] = rsqrtf((float)deg + 1.0f);
        }
    }
    __syncthreads();
    int padTot = padTotS;
    for (int i = tid; i < padTot; i += 256) csr[pbase + i] = NN;   // sentinel fill
    __syncthreads();
    for (int i = tid; i < n; i += 256) {
        int p = sbuf[i];
        int pos = atomicAdd(&cur[p & 127], 1);
        csr[pbase + pos] = p >> 7;
    }
}

// LDS-tiled layer-1 GEMM; epilogue writes y1 in SLICE-BLOCKED layout:
// slice s (cols 16s..16s+15) contiguous, region stride (NN+1)*16 bf16 (3.2 MB).
__global__ void k_gemm1(const float* __restrict__ x, const float* __restrict__ W1,
                        const float* __restrict__ dinv, bf16_t* __restrict__ y1b) {
    __shared__ float sx[64 * 66];
    __shared__ float sw[66 * 64];
    int tid = threadIdx.x;
    for (int i = tid; i < 66 * 32; i += 256) ((float2*)sw)[i] = ((const float2*)W1)[i];
    int base = blockIdx.x * 64;
    int rows = min(64, NN - base);
    int cnt2v = rows * 33;
    const float2* xp = (const float2*)(x + base * 66);
    for (int i = tid; i < cnt2v; i += 256) ((float2*)sx)[i] = xp[i];
    __syncthreads();
    int c = tid & 63, rg = tid >> 6;
    float acc[16];
#pragma unroll
    for (int i = 0; i < 16; ++i) acc[i] = 0.f;
    for (int k = 0; k < 66; ++k) {
        float wv = sw[k * 64 + c];
#pragma unroll
        for (int rr = 0; rr < 16; ++rr)
            acc[rr] = fmaf(sx[(rg * 16 + rr) * 66 + k], wv, acc[rr]);
    }
    bf16_t* dstp = y1b + (c >> 4) * ((NN + 1) * 16) + (c & 15);
#pragma unroll
    for (int rr = 0; rr < 16; ++rr) {
        int nn = base + rg * 16 + rr;
        if (nn < NN) dstp[nn * 16] = f2bf(dinv[nn] * acc[rr]);
        else if (nn == NN) dstp[nn * 16] = 0;     // sentinel zero row (all slices)
    }
}

// Slice-blocked CSR gather (R14-proven form): slice = blockIdx & (NSL-1) pins
// each XCD (blockIdx % 8) to ONE 3.2 MB slice region -> L2-resident y reads.
// Group of 8 lanes per node; one 32-B slice-row read per edge; 8-edge rounds;
// padded rows (sentinel NN -> zero row) -> no masking.
template<int NSL>   // 4 for C=64, 2 for C=32
__global__ __launch_bounds__(256) void k_gather(const int2* __restrict__ rowInfo,
                                                const int* __restrict__ csr,
                                                const float* __restrict__ dinv,
                                                const unsigned* __restrict__ yb,
                                                unsigned* __restrict__ aggb,
                                                float* __restrict__ sums,
                                                float* __restrict__ sqs) {
    constexpr int SH = (NSL == 4) ? 2 : 1;
    __shared__ float sSum[16], sSq[16];
    int tid = threadIdx.x;
    if (tid < 16) { sSum[tid] = 0.f; sSq[tid] = 0.f; }
    __syncthreads();
    int slice = blockIdx.x & (NSL - 1);
    int part = blockIdx.x >> SH;
    int nparts = gridDim.x >> SH;
    int lane = tid & 7;
    int grp = tid >> 3;                           // 32 node-groups per block
    const unsigned* y = yb + (size_t)slice * (NN + 1) * 8;
    unsigned* agg = aggb + (size_t)slice * NN * 8;
    float s0 = 0.f, s1 = 0.f, q0 = 0.f, q1 = 0.f;
    for (int n = part * 32 + grp; n < NN; n += nparts * 32) {
        int2 ri = rowInfo[n];
        float a0 = 0.f, a1 = 0.f;
        for (int j = ri.x; j < ri.y; j += 8) {
            const unsigned long long* cp = (const unsigned long long*)(csr + j);
            unsigned long long p0 = __builtin_nontemporal_load(cp);
            unsigned long long p1 = __builtin_nontemporal_load(cp + 1);
            unsigned long long p2 = __builtin_nontemporal_load(cp + 2);
            unsigned long long p3 = __builtin_nontemporal_load(cp + 3);
            unsigned v0 = y[(int)(p0 & 0xffffffffu) * 8 + lane];
            unsigned v1 = y[(int)(p0 >> 32) * 8 + lane];
            unsigned v2 = y[(int)(p1 & 0xffffffffu) * 8 + lane];
            unsigned v3 = y[(int)(p1 >> 32) * 8 + lane];
            unsigned v4 = y[(int)(p2 & 0xffffffffu) * 8 + lane];
            unsigned v5 = y[(int)(p2 >> 32) * 8 + lane];
            unsigned v6 = y[(int)(p3 & 0xffffffffu) * 8 + lane];
            unsigned v7 = y[(int)(p3 >> 32) * 8 + lane];
            a0 += bflo(v0); a1 += bfhi(v0);
            a0 += bflo(v1); a1 += bfhi(v1);
            a0 += bflo(v2); a1 += bfhi(v2);
            a0 += bflo(v3); a1 += bfhi(v3);
            a0 += bflo(v4); a1 += bfhi(v4);
            a0 += bflo(v5); a1 += bfhi(v5);
            a0 += bflo(v6); a1 += bfhi(v6);
            a0 += bflo(v7); a1 += bfhi(v7);
        }
        unsigned vs = y[n * 8 + lane];            // self loop
        float di = dinv[n];
        a0 = di * (a0 + bflo(vs));
        a1 = di * (a1 + bfhi(vs));
        agg[n * 8 + lane] = bfpack(a0, a1);
        s0 += a0; q0 += a0 * a0;
        s1 += a1; q1 += a1 * a1;
    }
    atomicAdd(&sSum[lane * 2], s0);
    atomicAdd(&sSum[lane * 2 + 1], s1);
    atomicAdd(&sSq[lane * 2], q0);
    atomicAdd(&sSq[lane * 2 + 1], q1);
    __syncthreads();
    if (tid < 16) {
        unsafeAtomicAdd(&sums[slice * 16 + tid], sSum[tid]);
        unsafeAtomicAdd(&sqs[slice * 16 + tid], sSq[tid]);
    }
}

// fused: scale/shift from sums/sqs, h1 = elu(bn(agg1)) in LDS, y2 = dinv*(h1@W2).
// agg1 read slice-blocked; y2 written slice-blocked (2 slices). +1 block for sentinel.
__global__ void k_bn_gemm2(const unsigned* __restrict__ agg1b, const float* __restrict__ sums,
                           const float* __restrict__ sqs, const float* __restrict__ gamma,
                           const float* __restrict__ beta, const float* __restrict__ W2,
                           const float* __restrict__ dinv, bf16_t* __restrict__ y2b) {
    __shared__ float sh[8 * 64];
    __shared__ float sW[64 * 32];
    __shared__ float sscale[64], sshift[64];
    int tid = threadIdx.x;
    if (tid < 64) {
        float mu = sums[tid] * (1.0f / NN);
        float var = sqs[tid] * (1.0f / NN) - mu * mu;
        float sc = gamma[tid] * rsqrtf(var + 1e-5f);
        sscale[tid] = sc;
        sshift[tid] = beta[tid] - mu * sc;
    }
#pragma unroll
    for (int i = tid; i < 64 * 32; i += 256) sW[i] = W2[i];
    __syncthreads();
    int base = blockIdx.x * 8;
    {   // load 8 rows x 64 cols from 4 slice regions: thread t -> one uint (2 cols)
        int r = tid >> 5, q = tid & 31;
        int slice = q >> 3, lane = q & 7;
        int n = base + r;
        int col = slice * 16 + lane * 2;
        float v0 = 0.f, v1 = 0.f;
        if (n < NN) {
            unsigned u = agg1b[(size_t)slice * NN * 8 + n * 8 + lane];
            v0 = eluf(fmaf(bflo(u), sscale[col], sshift[col]));
            v1 = eluf(fmaf(bfhi(u), sscale[col + 1], sshift[col + 1]));
        }
        sh[r * 64 + col] = v0;
        sh[r * 64 + col + 1] = v1;
    }
    __syncthreads();
    int r = tid >> 5, c = tid & 31;
    int n = base + r;
    bf16_t* dstp = y2b + (c >> 4) * ((NN + 1) * 16) + (c & 15);
    if (n < NN) {
        float acc = 0.f;
#pragma unroll
        for (int k = 0; k < 64; ++k) acc = fmaf(sh[r * 64 + k], sW[k * 32 + c], acc);
        dstp[n * 16] = f2bf(dinv[n] * acc);
    } else if (n == NN) {
        dstp[n * 16] = 0;                         // sentinel zero row
    }
}

// fused: BN stats -> scale/shift, segment pool (no atomics), 2-layer MLP head.
// agg2 read from slice-blocked layout (2 slices of 16 cols).
__global__ void k_poolmlp(const unsigned* __restrict__ agg2b, const float* __restrict__ sums,
                          const float* __restrict__ sqs, const float* __restrict__ gamma,
                          const float* __restrict__ beta, const int* __restrict__ gptr,
                          const float* __restrict__ Wm1, const float* __restrict__ bm1,
                          const float* __restrict__ Wm2, const float* __restrict__ bm2,
                          float* __restrict__ out) {
    __shared__ float sscale[32], sshift[32];
    __shared__ float red[256];
    __shared__ float gr[64];
    __shared__ float h[32];
    int tid = threadIdx.x;
    if (tid < 32) {
        float mu = sums[tid] * (1.0f / NN);
        float var = sqs[tid] * (1.0f / NN) - mu * mu;
        float sc = gamma[tid] * rsqrtf(var + 1e-5f);
        sscale[tid] = sc;
        sshift[tid] = beta[tid] - mu * sc;
    }
    __syncthreads();
    int g = blockIdx.x;
    int c = tid & 31, r = tid >> 5;
    int beg = gptr[g], end = gptr[g + 1];
    float scl = sscale[c], shf = sshift[c];
    const unsigned* ap = agg2b + (size_t)(c >> 4) * NN * 8 + ((c >> 1) & 7);
    bool hi = (c & 1);
    float s = 0.f, m = -INFINITY;
    for (int n = beg + r; n < end; n += 8) {
        unsigned u = ap[n * 8];
        float v = eluf(fmaf(hi ? bfhi(u) : bflo(u), scl, shf));
        s += v;
        m = fmaxf(m, v);
    }
    red[tid] = s;
    __syncthreads();
    int cnt = end - beg;
    if (r == 0) {
        float stot = 0.f;
#pragma unroll
        for (int i = 0; i < 8; ++i) stot += red[i * 32 + c];
        gr[c] = stot / fmaxf((float)cnt, 1.f);
    }
    __syncthreads();
    red[tid] = m;
    __syncthreads();
    if (r == 0) {
        float mtot = -INFINITY;
#pragma unroll
        for (int i = 0; i < 8; ++i) mtot = fmaxf(mtot, red[i * 32 + c]);
        gr[32 + c] = (cnt > 0) ? mtot : 0.f;
    }
    __syncthreads();
    if (tid < 32) {
        float acc = bm1[tid];
#pragma unroll
        for (int k = 0; k < 64; ++k) acc = fmaf(gr[k], Wm1[k * 32 + tid], acc);
        h[tid] = eluf(acc);
    }
    __syncthreads();
    if (tid < 2) {
        float acc = bm2[tid];
#pragma unroll
        for (int k = 0; k < 32; ++k) acc = fmaf(h[k], Wm2[k * 2 + tid], acc);
        out[g * 2 + tid] = acc;
    }
}

extern "C" void kernel_launch(void* const* d_in, const int* in_sizes, int n_in,
                              void* d_out, int out_size, void* d_ws, size_t ws_size,
                              hipStream_t stream) {
    const float* x    = (const float*)d_in[0];
    const int*   eidx = (const int*)d_in[1];
    const int*   src  = eidx;
    const int*   dst  = eidx + NE;
    const int*   batch = (const int*)d_in[3];
    const float* W1  = (const float*)d_in[4];
    const float* g1  = (const float*)d_in[6];
    const float* be1 = (const float*)d_in[7];
    const float* W2  = (const float*)d_in[8];
    const float* g2  = (const float*)d_in[10];
    const float* be2 = (const float*)d_in[11];
    const float* Wm1 = (const float*)d_in[12];
    const float* bm1 = (const float*)d_in[13];
    const float* Wm2 = (const float*)d_in[14];
    const float* bm2 = (const float*)d_in[15];
    float* out = (float*)d_out;

    // ---- workspace layout ----
    constexpr int CSRSZ = NBKT * PADREG + 16;     // fixed-stride padded csr (~10.8 MB)
    int*    bktCur  = (int*)d_ws;                 // 800 -- zeroed
    float*  S       = (float*)(bktCur + 800);     // 512 stat floats -- zeroed
    int*    gptr    = (int*)(S + 512);            // 544
    int*    csr     = gptr + 544;                 // CSRSZ (8-aligned rows)
    int2*   rowInfo = (int2*)(csr + CSRSZ);       // 100000
    float*  dinv    = (float*)(rowInfo + 100000); // 100000
    bf16_t* y1b     = (bf16_t*)(dinv + 100000);   // 4 slices x (NN+1)*16
    bf16_t* agg1b   = y1b + (NN + 1) * 64;        // 4 slices x NN*16
    bf16_t* y2b     = agg1b + NN * 64;            // 2 slices x (NN+1)*16
    bf16_t* agg2b   = y2b + (NN + 1) * 32;        // 2 slices x NN*16
    int*    ebuf    = (int*)y2b;                  // NBKT*BSTR ints (8 MB), aliases y2/agg2

    float* sum1 = S;        float* sq1 = S + 64;
    float* sum2 = S + 128;  float* sq2 = S + 160;

    // ---- init: bucket cursors + stats in one memset ----
    hipMemsetAsync(bktCur, 0, (800 + 512) * sizeof(int), stream);

    // ---- CSR build: LDS-agg fixed-stride scatter -> padded bucket sort (+gptr) ----
    k_scatter_bkt<<<384, 256, 0, stream>>>(src, dst, bktCur, ebuf);
    k_bktsort<<<NBKT + 1, 256, 0, stream>>>(bktCur, ebuf, csr, rowInfo, dinv, batch, gptr);

    // ---- layer 1 (bias dropped: BN shift-invariant; y1 = dinv * xW1, blocked) ----
    k_gemm1<<<(NN + 63) / 64, 256, 0, stream>>>(x, W1, dinv, y1b);
    k_gather<4><<<4096, 256, 0, stream>>>(rowInfo, csr, dinv,
                                          (const unsigned*)y1b, (unsigned*)agg1b,
                                          sum1, sq1);

    // ---- layer 2 (BN+ELU+stats fused into GEMM; y2 = dinv * h1W2, blocked) ----
    k_bn_gemm2<<<NN / 8 + 1, 256, 0, stream>>>((const unsigned*)agg1b, sum1, sq1,
                                               g1, be1, W2, dinv, y2b);
    k_gather<2><<<2048, 256, 0, stream>>>(rowInfo, csr, dinv,
                                          (const unsigned*)y2b, (unsigned*)agg2b,
                                          sum2, sq2);

    // ---- pooling + MLP head in one kernel ----
    k_poolmlp<<<NG, 256, 0, stream>>>((const unsigned*)agg2b, sum2, sq2, g2, be2, gptr,
                                      Wm1, bm1, Wm2, bm2, out);
}